// Round 7
// baseline (1386.414 us; speedup 1.0000x reference)
//
#include <hip/hip_runtime.h>
#include <math.h>

// ---- problem constants ----
#define NN     50000
#define NE     400000
#define INDIM  256
#define NH     128
#define NTYPE  4
#define NREL   5
#define NHEAD  4
#define DK     32
#define RSQRT_DK 0.17677669529663687f
#define BN     64
#define NSCAN_BLK ((NN + 255) / 256)   // 196

__device__ __forceinline__ float gelu_f(float x){
    return 0.5f * x * (1.0f + erff(x * 0.70710678118654752f));
}
__device__ __forceinline__ float bf2f(unsigned short u){
    return __uint_as_float(((unsigned)u) << 16);
}
__device__ __forceinline__ unsigned short f2bf(float f){
    unsigned u = __float_as_uint(f);
    u += 0x7fff + ((u >> 16) & 1);          // round-to-nearest-even
    return (unsigned short)(u >> 16);
}

// ---------------- node bucketing by type ----------------
__global__ void GNN_nscatter(const int* __restrict__ ntype, int* __restrict__ ncur,
                             int* __restrict__ nperm){
    __shared__ int lcnt[4], lbase[4];
    int tid = threadIdx.x;
    if (tid < 4) lcnt[tid] = 0;
    __syncthreads();
    int n = blockIdx.x * 256 + tid;
    int t = 0, lpos = 0;
    bool ok = (n < NN);
    if (ok){ t = ntype[n]; lpos = atomicAdd(&lcnt[t], 1); }
    __syncthreads();
    if (tid < 4 && lcnt[tid] > 0) lbase[tid] = atomicAdd(&ncur[tid], lcnt[tid]);
    __syncthreads();
    if (ok) nperm[t * NN + lbase[t] + lpos] = n;
}

// ---------------- CSR by destination ----------------
__global__ void GNN_deg(const int* __restrict__ edst, int* __restrict__ deg){
    int e = blockIdx.x * 256 + threadIdx.x;
    if (e < NE) atomicAdd(&deg[edst[e]], 1);
}

__global__ void GNN_scan1(const int* __restrict__ deg, int* __restrict__ rowptr,
                          int* __restrict__ bsum){
    __shared__ int s[256];
    int g = blockIdx.x * 256 + threadIdx.x;
    int v = (g < NN) ? deg[g] : 0;
    s[threadIdx.x] = v;
    __syncthreads();
    for (int off = 1; off < 256; off <<= 1){
        int t = (threadIdx.x >= off) ? s[threadIdx.x - off] : 0;
        __syncthreads();
        s[threadIdx.x] += t;
        __syncthreads();
    }
    if (g < NN) rowptr[g] = s[threadIdx.x] - v;
    if (threadIdx.x == 255) bsum[blockIdx.x] = s[255];
}

__global__ void GNN_scan2(const int* __restrict__ bsum, int* __restrict__ bbase){
    __shared__ int s[256];
    int v = (threadIdx.x < NSCAN_BLK) ? bsum[threadIdx.x] : 0;
    s[threadIdx.x] = v;
    __syncthreads();
    for (int off = 1; off < 256; off <<= 1){
        int t = (threadIdx.x >= off) ? s[threadIdx.x - off] : 0;
        __syncthreads();
        s[threadIdx.x] += t;
        __syncthreads();
    }
    bbase[threadIdx.x] = s[threadIdx.x] - v;
}

__global__ void GNN_scan3(int* __restrict__ rowptr, const int* __restrict__ bbase){
    int g = blockIdx.x * 256 + threadIdx.x;
    if (g < NN) rowptr[g] += bbase[blockIdx.x];
    if (g == 0) rowptr[NN] = NE;
}

__global__ void GNN_csr_scatter(const int* __restrict__ edst, const int* __restrict__ rowptr,
                                int* __restrict__ cursor, int* __restrict__ csr_e){
    int e = blockIdx.x * 256 + threadIdx.x;
    if (e >= NE) return;
    int d = edst[e];
    int pos = atomicAdd(&cursor[d], 1);
    csr_e[rowptr[d] + pos] = e;
}

// ------------- per-type tiled GEMM: OUT = epilogue(X @ W[t] + b[t])
// MODE 0: gelu(.)   MODE 2: (.)*sig(skip[t]) + Hprev*(1-sig(skip[t]))
template<int MODE>
__global__ __launch_bounds__(256) void GNN_ptype_gemm(
    const float* __restrict__ X, int K,
    const float* __restrict__ Wall, const float* __restrict__ ball,
    const float* __restrict__ skiprow, const float* __restrict__ Hprev,
    const int* __restrict__ nperm, const int* __restrict__ counts,
    float* __restrict__ OUT)
{
    int t = blockIdx.y;
    int cnt = counts[t];
    int rbase = blockIdx.x * BN;
    if (rbase >= cnt) return;
    const float* W = Wall + (size_t)t * K * NH;
    __shared__ float Xs[BN][33];
    __shared__ float Ws[32][NH];
    __shared__ int nids[BN];
    int tid = threadIdx.x;
    if (tid < BN){
        int idx = rbase + tid;
        nids[tid] = (idx < cnt) ? nperm[t * NN + idx] : -1;
    }
    int cq = tid & 31;
    int rq = tid >> 5;
    float acc[8][4];
    #pragma unroll
    for (int i = 0; i < 8; i++){ acc[i][0]=0.f; acc[i][1]=0.f; acc[i][2]=0.f; acc[i][3]=0.f; }
    __syncthreads();
    for (int k0 = 0; k0 < K; k0 += 32){
        {
            int lr = tid >> 3;
            int lc = (tid & 7) * 4;
            #pragma unroll
            for (int h2 = 0; h2 < 2; h2++){
                int r = lr + 32 * h2;
                int nid = nids[r];
                float4 xv = make_float4(0.f, 0.f, 0.f, 0.f);
                if (nid >= 0) xv = *(const float4*)(X + (size_t)nid * K + k0 + lc);
                Xs[r][lc+0]=xv.x; Xs[r][lc+1]=xv.y; Xs[r][lc+2]=xv.z; Xs[r][lc+3]=xv.w;
            }
        }
        {
            int wr = tid >> 5;
            int wc = (tid & 31) * 4;
            #pragma unroll
            for (int h2 = 0; h2 < 4; h2++){
                int r = wr + 8 * h2;
                *(float4*)&Ws[r][wc] = *(const float4*)(W + (size_t)(k0 + r) * NH + wc);
            }
        }
        __syncthreads();
        #pragma unroll
        for (int kk = 0; kk < 32; kk++){
            float4 wv = *(const float4*)&Ws[kk][cq * 4];
            #pragma unroll
            for (int i = 0; i < 8; i++){
                float xv = Xs[rq + 8*i][kk];
                acc[i][0] += xv * wv.x; acc[i][1] += xv * wv.y;
                acc[i][2] += xv * wv.z; acc[i][3] += xv * wv.w;
            }
        }
        __syncthreads();
    }
    float b0 = ball[t*NH + cq*4 + 0];
    float b1 = ball[t*NH + cq*4 + 1];
    float b2 = ball[t*NH + cq*4 + 2];
    float b3 = ball[t*NH + cq*4 + 3];
    float a_t = 0.f, one_m = 0.f;
    if (MODE == 2){ a_t = 1.f / (1.f + expf(-skiprow[t])); one_m = 1.f - a_t; }
    #pragma unroll
    for (int i = 0; i < 8; i++){
        int r = rq + 8*i;
        int nid = nids[r];
        if (nid < 0) continue;
        float v0 = acc[i][0] + b0, v1 = acc[i][1] + b1;
        float v2 = acc[i][2] + b2, v3 = acc[i][3] + b3;
        if (MODE == 0){ v0 = gelu_f(v0); v1 = gelu_f(v1); v2 = gelu_f(v2); v3 = gelu_f(v3); }
        if (MODE == 2){
            float4 hp = *(const float4*)(Hprev + (size_t)nid * NH + cq * 4);
            v0 = v0 * a_t + hp.x * one_m; v1 = v1 * a_t + hp.y * one_m;
            v2 = v2 * a_t + hp.z * one_m; v3 = v3 * a_t + hp.w * one_m;
        }
        *(float4*)(OUT + (size_t)nid * NH + cq * 4) = make_float4(v0, v1, v2, v3);
    }
}

// ------------- fused Q/K/V per-type GEMM: X-tile resident in LDS, 3 weight passes --------
__global__ __launch_bounds__(256) void GNN_qkv(
    const float* __restrict__ X,
    const float* __restrict__ WqL, const float* __restrict__ WkL, const float* __restrict__ WvL,
    const float* __restrict__ bqL, const float* __restrict__ bkL, const float* __restrict__ bvL,
    const int* __restrict__ nperm, const int* __restrict__ counts,
    float* __restrict__ Qn, float* __restrict__ Kn, float* __restrict__ Vn)
{
    int t = blockIdx.y;
    int cnt = counts[t];
    int rbase = blockIdx.x * BN;
    if (rbase >= cnt) return;
    __shared__ float Xs[BN * 132];
    __shared__ float Ws[32 * NH];
    __shared__ int nids[BN];
    int tid = threadIdx.x;
    if (tid < BN){
        int idx = rbase + tid;
        nids[tid] = (idx < cnt) ? nperm[t * NN + idx] : -1;
    }
    __syncthreads();
    #pragma unroll
    for (int rep = 0; rep < 8; rep++){
        int idx = tid + rep * 256;
        int row = idx >> 5;
        int c4 = (idx & 31) * 4;
        int nid = nids[row];
        float4 xv = make_float4(0.f, 0.f, 0.f, 0.f);
        if (nid >= 0) xv = *(const float4*)(X + (size_t)nid * NH + c4);
        *(float4*)&Xs[row * 132 + c4] = xv;
    }
    int cq = tid & 31;
    int rq = tid >> 5;
    for (int m = 0; m < 3; m++){
        const float* W = ((m == 0) ? WqL : (m == 1) ? WkL : WvL) + (size_t)t * NH * NH;
        const float* bb = ((m == 0) ? bqL : (m == 1) ? bkL : bvL) + t * NH;
        float* OUT = (m == 0) ? Qn : (m == 1) ? Kn : Vn;
        float acc[8][4];
        #pragma unroll
        for (int i = 0; i < 8; i++){ acc[i][0]=0.f; acc[i][1]=0.f; acc[i][2]=0.f; acc[i][3]=0.f; }
        for (int k0 = 0; k0 < NH; k0 += 32){
            __syncthreads();
            {
                int wr = tid >> 5;
                int wc = (tid & 31) * 4;
                #pragma unroll
                for (int h2 = 0; h2 < 4; h2++){
                    int r = wr + 8 * h2;
                    *(float4*)&Ws[r * NH + wc] = *(const float4*)(W + (size_t)(k0 + r) * NH + wc);
                }
            }
            __syncthreads();
            #pragma unroll
            for (int kk = 0; kk < 32; kk++){
                float4 wv = *(const float4*)&Ws[kk * NH + cq * 4];
                #pragma unroll
                for (int i = 0; i < 8; i++){
                    float xv = Xs[(rq + 8*i) * 132 + k0 + kk];
                    acc[i][0] += xv * wv.x; acc[i][1] += xv * wv.y;
                    acc[i][2] += xv * wv.z; acc[i][3] += xv * wv.w;
                }
            }
        }
        float b0 = bb[cq*4+0], b1 = bb[cq*4+1], b2 = bb[cq*4+2], b3 = bb[cq*4+3];
        #pragma unroll
        for (int i = 0; i < 8; i++){
            int nid = nids[rq + 8*i];
            if (nid < 0) continue;
            *(float4*)(OUT + (size_t)nid * NH + cq * 4) =
                make_float4(acc[i][0]+b0, acc[i][1]+b1, acc[i][2]+b2, acc[i][3]+b3);
        }
    }
}

// ------------- RTE tables ----------------
__global__ void GNN_rte_tab(const float* __restrict__ rte_emb, const float* __restrict__ rW,
                            const float* __restrict__ rb, float* __restrict__ tab){
    int m = blockIdx.x, j = threadIdx.x;
    __shared__ float e[NH];
    e[j] = rte_emb[m * NH + j];
    __syncthreads();
    float a = rb[j];
    #pragma unroll 8
    for (int d = 0; d < NH; d++) a += e[d] * rW[d * NH + j];
    tab[m * NH + j] = a;
}

__global__ void GNN_rte_proj(const float* __restrict__ tab, const float* __restrict__ WkL,
                             const float* __restrict__ WvL, float* __restrict__ RK,
                             float* __restrict__ RV){
    int m = blockIdx.x, j = threadIdx.x;
    int sel = blockIdx.y; int t = sel >> 1; int which = sel & 1;
    const float* W = (which ? WvL : WkL) + (size_t)t * NH * NH;
    float* O = which ? RV : RK;
    __shared__ float e[NH];
    e[j] = tab[m * NH + j];
    __syncthreads();
    float a = 0.f;
    #pragma unroll 8
    for (int d = 0; d < NH; d++) a += e[d] * W[d * NH + j];
    O[(size_t)(t * 240 + m) * NH + j] = a;
}

// ------------- row transform (bf16 out), per head h:
// TRANSPOSE=1 (QA):  out[d] = p * sum_c A[h][d][c] * x[h*32+c]   (contract 2nd idx)
// TRANSPOSE=0 (VM):  out[c] =     sum_d M[h][d][c] * x[h*32+d]   (contract 1st idx,
//                                 matches reference einsum 'ehd,hdk->ehk')
// Half-wave per row, 8 rows/half-wave, x held in registers across all 5 relations.
template<int SCALE, int TRANSPOSE>
__global__ __launch_bounds__(256) void GNN_xform(
    const float* __restrict__ X, int rows,
    const float* __restrict__ A5, const float* __restrict__ relP,
    unsigned short* __restrict__ outb)
{
    __shared__ float At[NHEAD * DK * DK];   // At[h*1024 + sum_idx*32 + out_idx]
    int tid = threadIdx.x;
    int hw = tid >> 5, lane = tid & 31, h = lane >> 3, dl = (lane & 7) * 4;
    float4 x4[8];
    #pragma unroll
    for (int it = 0; it < 8; it++){
        int row = blockIdx.x * 64 + it * 8 + hw;
        x4[it] = make_float4(0.f, 0.f, 0.f, 0.f);
        if (row < rows) x4[it] = *(const float4*)(X + (size_t)row * NH + lane * 4);
    }
    for (int r = 0; r < NREL; r++){
        __syncthreads();
        const float* Ar = A5 + (size_t)r * NHEAD * DK * DK;
        if (TRANSPOSE){
            for (int x = tid; x < NHEAD * DK * DK; x += 256){
                int hh = x >> 10, rem = x & 1023, dd = rem >> 5, cc = rem & 31;
                At[hh * 1024 + cc * 32 + dd] = Ar[x];   // [c][d] = A[d][c]
            }
        } else {
            for (int x = tid; x < NHEAD * DK * DK; x += 256) At[x] = Ar[x];  // [d][c]
        }
        __syncthreads();
        float p = 1.f;
        if (SCALE) p = relP[r * NHEAD + h] * RSQRT_DK;
        for (int it = 0; it < 8; it++){
            int row = blockIdx.x * 64 + it * 8 + hw;
            float4 q4 = x4[it];
            float ox = 0.f, oy = 0.f, oz = 0.f, ow = 0.f;
            #pragma unroll
            for (int c = 0; c < 32; c++){               // c = contraction index
                float comp = ((c & 3) == 0) ? q4.x : ((c & 3) == 1) ? q4.y
                           : ((c & 3) == 2) ? q4.z : q4.w;
                float qc = __shfl(comp, h * 8 + (c >> 2), 32);
                float4 av = *(const float4*)&At[h * 1024 + c * 32 + dl];
                ox += qc * av.x; oy += qc * av.y; oz += qc * av.z; ow += qc * av.w;
            }
            if (row < rows){
                size_t o = ((size_t)row * NREL + r) * NH + lane * 4;
                ushort4 s4;
                s4.x = f2bf(ox*p); s4.y = f2bf(oy*p); s4.z = f2bf(oz*p); s4.w = f2bf(ow*p);
                *(ushort4*)(outb + o) = s4;
            }
        }
    }
}

// ------------- fused attention: single-pass online softmax, no LDS, no att buffer --------
__global__ __launch_bounds__(256) void GNN_attn(
    const float* __restrict__ Kn, const float* __restrict__ RK,
    const unsigned short* __restrict__ QAb, const unsigned short* __restrict__ VMb,
    const unsigned short* __restrict__ RVMb,
    const int* __restrict__ rowptr, const int* __restrict__ csr_e,
    const int* __restrict__ esrc, const int* __restrict__ etype,
    const int* __restrict__ etime, const int* __restrict__ ntype,
    float* __restrict__ aggr)
{
    int tid = threadIdx.x;
    int hw = tid >> 5, lane = tid & 31;
    int i = blockIdx.x * 8 + hw;
    if (i >= NN) return;                    // no barriers in this kernel
    size_t qoff = (size_t)i * NREL * NH + lane * 4;
    ushort4 u0 = *(const ushort4*)(QAb + qoff);
    ushort4 u1 = *(const ushort4*)(QAb + qoff + NH);
    ushort4 u2 = *(const ushort4*)(QAb + qoff + 2 * NH);
    ushort4 u3 = *(const ushort4*)(QAb + qoff + 3 * NH);
    ushort4 u4 = *(const ushort4*)(QAb + qoff + 4 * NH);
    float4 qa0 = make_float4(bf2f(u0.x), bf2f(u0.y), bf2f(u0.z), bf2f(u0.w));
    float4 qa1 = make_float4(bf2f(u1.x), bf2f(u1.y), bf2f(u1.z), bf2f(u1.w));
    float4 qa2v = make_float4(bf2f(u2.x), bf2f(u2.y), bf2f(u2.z), bf2f(u2.w));
    float4 qa3 = make_float4(bf2f(u3.x), bf2f(u3.y), bf2f(u3.z), bf2f(u3.w));
    float4 qa4 = make_float4(bf2f(u4.x), bf2f(u4.y), bf2f(u4.z), bf2f(u4.w));
    int beg = rowptr[i], end = rowptr[i + 1];
    float mx = -3.4e38f, den = 0.f;
    float ax = 0.f, ay = 0.f, az = 0.f, aw = 0.f;
    int e = 0, s = 0, r = 0, tm = 0, st = 0;
    if (beg < end){ e = csr_e[beg]; s = esrc[e]; r = etype[e]; tm = etime[e]; st = ntype[s]; }
    for (int k = beg; k < end; k++){
        int e2 = 0, s2 = 0, r2 = 0, tm2 = 0, st2 = 0;
        if (k + 1 < end){                   // 1-deep index prefetch
            e2 = csr_e[k+1]; s2 = esrc[e2]; r2 = etype[e2]; tm2 = etime[e2]; st2 = ntype[s2];
        }
        float4 k4 = *(const float4*)(Kn + (size_t)s * NH + lane * 4);
        float4 rk = *(const float4*)(RK + (size_t)(st * 240 + tm) * NH + lane * 4);
        float4 q = (r == 0) ? qa0 : (r == 1) ? qa1 : (r == 2) ? qa2v : (r == 3) ? qa3 : qa4;
        float pv = (k4.x + rk.x) * q.x + (k4.y + rk.y) * q.y
                 + (k4.z + rk.z) * q.z + (k4.w + rk.w) * q.w;
        pv += __shfl_xor(pv, 1, 32);
        pv += __shfl_xor(pv, 2, 32);
        pv += __shfl_xor(pv, 4, 32);        // all 8 lanes of the head now hold the score
        float a = pv;                       // relP/sqrt(dk) already folded into QA
        if (a > mx){
            float sc = expf(mx - a);        // first edge: expf(-3.4e38-a) == 0
            den *= sc; ax *= sc; ay *= sc; az *= sc; aw *= sc;
            mx = a;
        }
        float ex = expf(a - mx);
        den += ex;
        ushort4 vm4 = *(const ushort4*)(VMb + ((size_t)s * NREL + r) * NH + lane * 4);
        ushort4 rv4 = *(const ushort4*)(RVMb + ((size_t)(st * 240 + tm) * NREL + r) * NH + lane * 4);
        float vx = bf2f(vm4.x) + bf2f(rv4.x);
        float vy = bf2f(vm4.y) + bf2f(rv4.y);
        float vz = bf2f(vm4.z) + bf2f(rv4.z);
        float vw = bf2f(vm4.w) + bf2f(rv4.w);
        ax += ex * vx; ay += ex * vy; az += ex * vz; aw += ex * vw;
        e = e2; s = s2; r = r2; tm = tm2; st = st2;
    }
    float inv = 1.f / (den + 1e-16f);
    *(float4*)(aggr + (size_t)i * NH + lane * 4) =
        make_float4(gelu_f(ax * inv), gelu_f(ay * inv), gelu_f(az * inv), gelu_f(aw * inv));
}

extern "C" void kernel_launch(void* const* d_in, const int* in_sizes, int n_in,
                              void* d_out, int out_size, void* d_ws, size_t ws_size,
                              hipStream_t stream)
{
    const float* node_feature = (const float*)d_in[0];
    const float* adapt_W = (const float*)d_in[1];
    const float* adapt_b = (const float*)d_in[2];
    const float* Wk = (const float*)d_in[3];
    const float* bk = (const float*)d_in[4];
    const float* Wq = (const float*)d_in[5];
    const float* bq = (const float*)d_in[6];
    const float* Wv = (const float*)d_in[7];
    const float* bv = (const float*)d_in[8];
    const float* Wa = (const float*)d_in[9];
    const float* ba = (const float*)d_in[10];
    const float* rel_pri = (const float*)d_in[11];
    const float* rel_att = (const float*)d_in[12];
    const float* rel_msg = (const float*)d_in[13];
    const float* skip = (const float*)d_in[14];
    const float* rte_emb = (const float*)d_in[15];
    const float* rte_W = (const float*)d_in[16];
    const float* rte_b = (const float*)d_in[17];
    const int* node_type = (const int*)d_in[18];
    const int* edge_index = (const int*)d_in[19];
    const int* edge_type = (const int*)d_in[20];
    const int* edge_time = (const int*)d_in[21];
    const int* esrc = edge_index;          // row 0 = source j
    const int* edst = edge_index + NE;     // row 1 = target i

    // workspace budget: ~236 MB total (round-3-proven bound; round-5's 299 MB crashed)
    char* p = (char*)d_ws;
    auto alloc = [&](size_t bytes) -> char* {
        char* r = p; p += (bytes + 255) & ~(size_t)255; return r;
    };
    float* hA    = (float*)alloc((size_t)NN * NH * 4);
    float* Qn    = (float*)alloc((size_t)NN * NH * 4);   // aggr aliases this after xform(Q)
    float* Kn    = (float*)alloc((size_t)NN * NH * 4);
    float* Vn    = (float*)alloc((size_t)NN * NH * 4);
    unsigned short* QAb  = (unsigned short*)alloc((size_t)NN * NREL * NH * 2);   // 64 MB bf16
    unsigned short* VMb  = (unsigned short*)alloc((size_t)NN * NREL * NH * 2);   // 64 MB bf16
    unsigned short* RVMb = (unsigned short*)alloc((size_t)NTYPE * 240 * NREL * NH * 2);
    float* rtab  = (float*)alloc((size_t)240 * NH * 4);
    float* RK    = (float*)alloc((size_t)NTYPE * 240 * NH * 4);
    float* RV    = (float*)alloc((size_t)NTYPE * 240 * NH * 4);
    int* nperm   = (int*)alloc((size_t)NTYPE * NN * 4);
    int* rowptr  = (int*)alloc((size_t)(NN + 1) * 4);
    int* csr_e   = (int*)alloc((size_t)NE * 4);
    int* deg     = (int*)alloc((size_t)2 * NN * 4);      // deg+cursor one block: one memset
    int* cursor  = deg + NN;
    int* bsum    = (int*)alloc(256 * 4);
    int* bbase   = (int*)alloc(256 * 4);
    int* ncur    = (int*)alloc(64);
    float* aggr  = Qn;    // Qn dead after GNN_xform(QA)

    hipMemsetAsync(ncur, 0, 64, stream);
    hipMemsetAsync(deg, 0, (size_t)2 * NN * 4, stream);

    GNN_nscatter<<<(NN + 255) / 256, 256, 0, stream>>>(node_type, ncur, nperm);
    GNN_deg<<<(NE + 255) / 256, 256, 0, stream>>>(edst, deg);
    GNN_scan1<<<NSCAN_BLK, 256, 0, stream>>>(deg, rowptr, bsum);
    GNN_scan2<<<1, 256, 0, stream>>>(bsum, bbase);
    GNN_scan3<<<NSCAN_BLK, 256, 0, stream>>>(rowptr, bbase);
    GNN_csr_scatter<<<(NE + 255) / 256, 256, 0, stream>>>(edst, rowptr, cursor, csr_e);

    dim3 ggrid((NN + BN - 1) / BN, NTYPE);
    GNN_ptype_gemm<0><<<ggrid, 256, 0, stream>>>(node_feature, INDIM, adapt_W, adapt_b,
                                                 nullptr, nullptr, nperm, ncur, hA);
    const float* hin = hA;
    for (int l = 0; l < 2; l++){
        const float* WkL = Wk + (size_t)l * NTYPE * NH * NH;
        const float* WqL = Wq + (size_t)l * NTYPE * NH * NH;
        const float* WvL = Wv + (size_t)l * NTYPE * NH * NH;
        const float* WaL = Wa + (size_t)l * NTYPE * NH * NH;
        const float* bkL = bk + (size_t)l * NTYPE * NH;
        const float* bqL = bq + (size_t)l * NTYPE * NH;
        const float* bvL = bv + (size_t)l * NTYPE * NH;
        const float* baL = ba + (size_t)l * NTYPE * NH;
        const float* relA = rel_att + (size_t)l * NREL * NHEAD * DK * DK;
        const float* relM = rel_msg + (size_t)l * NREL * NHEAD * DK * DK;
        const float* relP = rel_pri + (size_t)l * NREL * NHEAD;

        GNN_rte_tab<<<240, 128, 0, stream>>>(rte_emb, rte_W + (size_t)l * NH * NH,
                                             rte_b + (size_t)l * NH, rtab);
        GNN_rte_proj<<<dim3(240, NTYPE * 2), 128, 0, stream>>>(rtab, WkL, WvL, RK, RV);

        GNN_qkv<<<ggrid, 256, 0, stream>>>(hin, WqL, WkL, WvL, bqL, bkL, bvL,
                                           nperm, ncur, Qn, Kn, Vn);

        // QA: contract A's 2nd index (k . A q)  -> TRANSPOSE=1
        GNN_xform<1,1><<<(NN + 63) / 64, 256, 0, stream>>>(Qn, NN, relA, relP, QAb);
        // VM/RVM: contract M's 1st index (v^T M) -> TRANSPOSE=0  (R6 bug: had =1)
        GNN_xform<0,0><<<(NN + 63) / 64, 256, 0, stream>>>(Vn, NN, relM, nullptr, VMb);
        GNN_xform<0,0><<<(NTYPE * 240 + 63) / 64, 256, 0, stream>>>(RV, NTYPE * 240, relM,
                                                                    nullptr, RVMb);

        GNN_attn<<<(NN + 7) / 8, 256, 0, stream>>>(
            Kn, RK, QAb, VMb, RVMb, rowptr, csr_e, esrc, edge_type, edge_time, node_type,
            aggr);

        float* hout = (l == 0) ? hA : (float*)d_out;   // l==0 in-place on hA is safe:
        GNN_ptype_gemm<2><<<ggrid, 256, 0, stream>>>(  // epilogue reads Hprev elem then
            aggr, NH, WaL, baL, skip + (size_t)l * NTYPE, hin,   // writes same elem, same thread
            nperm, ncur, hout);
        hin = hout;
    }
}

// Round 8
// 1349.699 us; speedup vs baseline: 1.0272x; 1.0272x over previous
//
#include <hip/hip_runtime.h>
#include <math.h>

// ---- problem constants ----
#define NN     50000
#define NE     400000
#define INDIM  256
#define NH     128
#define NTYPE  4
#define NREL   5
#define NHEAD  4
#define DK     32
#define RSQRT_DK 0.17677669529663687f
#define BN     64
#define NSCAN_BLK ((NN + 255) / 256)   // 196

__device__ __forceinline__ float gelu_f(float x){
    return 0.5f * x * (1.0f + erff(x * 0.70710678118654752f));
}
__device__ __forceinline__ float bf2f(unsigned short u){
    return __uint_as_float(((unsigned)u) << 16);
}
__device__ __forceinline__ unsigned short f2bf(float f){
    unsigned u = __float_as_uint(f);
    u += 0x7fff + ((u >> 16) & 1);          // round-to-nearest-even
    return (unsigned short)(u >> 16);
}

// ---------------- node bucketing by type ----------------
__global__ void GNN_nscatter(const int* __restrict__ ntype, int* __restrict__ ncur,
                             int* __restrict__ nperm){
    __shared__ int lcnt[4], lbase[4];
    int tid = threadIdx.x;
    if (tid < 4) lcnt[tid] = 0;
    __syncthreads();
    int n = blockIdx.x * 256 + tid;
    int t = 0, lpos = 0;
    bool ok = (n < NN);
    if (ok){ t = ntype[n]; lpos = atomicAdd(&lcnt[t], 1); }
    __syncthreads();
    if (tid < 4 && lcnt[tid] > 0) lbase[tid] = atomicAdd(&ncur[tid], lcnt[tid]);
    __syncthreads();
    if (ok) nperm[t * NN + lbase[t] + lpos] = n;
}

// ---------------- CSR by destination ----------------
__global__ void GNN_deg(const int* __restrict__ edst, int* __restrict__ deg){
    int e = blockIdx.x * 256 + threadIdx.x;
    if (e < NE) atomicAdd(&deg[edst[e]], 1);
}

__global__ void GNN_scan1(const int* __restrict__ deg, int* __restrict__ rowptr,
                          int* __restrict__ bsum){
    __shared__ int s[256];
    int g = blockIdx.x * 256 + threadIdx.x;
    int v = (g < NN) ? deg[g] : 0;
    s[threadIdx.x] = v;
    __syncthreads();
    for (int off = 1; off < 256; off <<= 1){
        int t = (threadIdx.x >= off) ? s[threadIdx.x - off] : 0;
        __syncthreads();
        s[threadIdx.x] += t;
        __syncthreads();
    }
    if (g < NN) rowptr[g] = s[threadIdx.x] - v;
    if (threadIdx.x == 255) bsum[blockIdx.x] = s[255];
}

__global__ void GNN_scan2(const int* __restrict__ bsum, int* __restrict__ bbase){
    __shared__ int s[256];
    int v = (threadIdx.x < NSCAN_BLK) ? bsum[threadIdx.x] : 0;
    s[threadIdx.x] = v;
    __syncthreads();
    for (int off = 1; off < 256; off <<= 1){
        int t = (threadIdx.x >= off) ? s[threadIdx.x - off] : 0;
        __syncthreads();
        s[threadIdx.x] += t;
        __syncthreads();
    }
    bbase[threadIdx.x] = s[threadIdx.x] - v;
}

__global__ void GNN_scan3(int* __restrict__ rowptr, const int* __restrict__ bbase){
    int g = blockIdx.x * 256 + threadIdx.x;
    if (g < NN) rowptr[g] += bbase[blockIdx.x];
    if (g == 0) rowptr[NN] = NE;
}

__global__ void GNN_csr_scatter(const int* __restrict__ edst, const int* __restrict__ rowptr,
                                int* __restrict__ cursor, int* __restrict__ csr_e){
    int e = blockIdx.x * 256 + threadIdx.x;
    if (e >= NE) return;
    int d = edst[e];
    int pos = atomicAdd(&cursor[d], 1);
    csr_e[rowptr[d] + pos] = e;
}

// ------------- per-type tiled GEMM: OUT = epilogue(X @ W[t] + b[t])
// MODE 0: gelu(.)   MODE 2: (.)*sig(skip[t]) + Hprev*(1-sig(skip[t]))
template<int MODE>
__global__ __launch_bounds__(256) void GNN_ptype_gemm(
    const float* __restrict__ X, int K,
    const float* __restrict__ Wall, const float* __restrict__ ball,
    const float* __restrict__ skiprow, const float* __restrict__ Hprev,
    const int* __restrict__ nperm, const int* __restrict__ counts,
    float* __restrict__ OUT)
{
    int t = blockIdx.y;
    int cnt = counts[t];
    int rbase = blockIdx.x * BN;
    if (rbase >= cnt) return;
    const float* W = Wall + (size_t)t * K * NH;
    __shared__ float Xs[BN][33];
    __shared__ float Ws[32][NH];
    __shared__ int nids[BN];
    int tid = threadIdx.x;
    if (tid < BN){
        int idx = rbase + tid;
        nids[tid] = (idx < cnt) ? nperm[t * NN + idx] : -1;
    }
    int cq = tid & 31;
    int rq = tid >> 5;
    float acc[8][4];
    #pragma unroll
    for (int i = 0; i < 8; i++){ acc[i][0]=0.f; acc[i][1]=0.f; acc[i][2]=0.f; acc[i][3]=0.f; }
    __syncthreads();
    for (int k0 = 0; k0 < K; k0 += 32){
        {
            int lr = tid >> 3;
            int lc = (tid & 7) * 4;
            #pragma unroll
            for (int h2 = 0; h2 < 2; h2++){
                int r = lr + 32 * h2;
                int nid = nids[r];
                float4 xv = make_float4(0.f, 0.f, 0.f, 0.f);
                if (nid >= 0) xv = *(const float4*)(X + (size_t)nid * K + k0 + lc);
                Xs[r][lc+0]=xv.x; Xs[r][lc+1]=xv.y; Xs[r][lc+2]=xv.z; Xs[r][lc+3]=xv.w;
            }
        }
        {
            int wr = tid >> 5;
            int wc = (tid & 31) * 4;
            #pragma unroll
            for (int h2 = 0; h2 < 4; h2++){
                int r = wr + 8 * h2;
                *(float4*)&Ws[r][wc] = *(const float4*)(W + (size_t)(k0 + r) * NH + wc);
            }
        }
        __syncthreads();
        #pragma unroll
        for (int kk = 0; kk < 32; kk++){
            float4 wv = *(const float4*)&Ws[kk][cq * 4];
            #pragma unroll
            for (int i = 0; i < 8; i++){
                float xv = Xs[rq + 8*i][kk];
                acc[i][0] += xv * wv.x; acc[i][1] += xv * wv.y;
                acc[i][2] += xv * wv.z; acc[i][3] += xv * wv.w;
            }
        }
        __syncthreads();
    }
    float b0 = ball[t*NH + cq*4 + 0];
    float b1 = ball[t*NH + cq*4 + 1];
    float b2 = ball[t*NH + cq*4 + 2];
    float b3 = ball[t*NH + cq*4 + 3];
    float a_t = 0.f, one_m = 0.f;
    if (MODE == 2){ a_t = 1.f / (1.f + expf(-skiprow[t])); one_m = 1.f - a_t; }
    #pragma unroll
    for (int i = 0; i < 8; i++){
        int r = rq + 8*i;
        int nid = nids[r];
        if (nid < 0) continue;
        float v0 = acc[i][0] + b0, v1 = acc[i][1] + b1;
        float v2 = acc[i][2] + b2, v3 = acc[i][3] + b3;
        if (MODE == 0){ v0 = gelu_f(v0); v1 = gelu_f(v1); v2 = gelu_f(v2); v3 = gelu_f(v3); }
        if (MODE == 2){
            float4 hp = *(const float4*)(Hprev + (size_t)nid * NH + cq * 4);
            v0 = v0 * a_t + hp.x * one_m; v1 = v1 * a_t + hp.y * one_m;
            v2 = v2 * a_t + hp.z * one_m; v3 = v3 * a_t + hp.w * one_m;
        }
        *(float4*)(OUT + (size_t)nid * NH + cq * 4) = make_float4(v0, v1, v2, v3);
    }
}

// ------------- fused Q/K/V per-type GEMM: X-tile resident in LDS, 3 weight passes --------
// K output (m==1) is stored bf16 for the attention gather path.
__global__ __launch_bounds__(256) void GNN_qkv(
    const float* __restrict__ X,
    const float* __restrict__ WqL, const float* __restrict__ WkL, const float* __restrict__ WvL,
    const float* __restrict__ bqL, const float* __restrict__ bkL, const float* __restrict__ bvL,
    const int* __restrict__ nperm, const int* __restrict__ counts,
    float* __restrict__ Qn, unsigned short* __restrict__ Knb, float* __restrict__ Vn)
{
    int t = blockIdx.y;
    int cnt = counts[t];
    int rbase = blockIdx.x * BN;
    if (rbase >= cnt) return;
    __shared__ float Xs[BN * 132];
    __shared__ float Ws[32 * NH];
    __shared__ int nids[BN];
    int tid = threadIdx.x;
    if (tid < BN){
        int idx = rbase + tid;
        nids[tid] = (idx < cnt) ? nperm[t * NN + idx] : -1;
    }
    __syncthreads();
    #pragma unroll
    for (int rep = 0; rep < 8; rep++){
        int idx = tid + rep * 256;
        int row = idx >> 5;
        int c4 = (idx & 31) * 4;
        int nid = nids[row];
        float4 xv = make_float4(0.f, 0.f, 0.f, 0.f);
        if (nid >= 0) xv = *(const float4*)(X + (size_t)nid * NH + c4);
        *(float4*)&Xs[row * 132 + c4] = xv;
    }
    int cq = tid & 31;
    int rq = tid >> 5;
    for (int m = 0; m < 3; m++){
        const float* W = ((m == 0) ? WqL : (m == 1) ? WkL : WvL) + (size_t)t * NH * NH;
        const float* bb = ((m == 0) ? bqL : (m == 1) ? bkL : bvL) + t * NH;
        float acc[8][4];
        #pragma unroll
        for (int i = 0; i < 8; i++){ acc[i][0]=0.f; acc[i][1]=0.f; acc[i][2]=0.f; acc[i][3]=0.f; }
        for (int k0 = 0; k0 < NH; k0 += 32){
            __syncthreads();
            {
                int wr = tid >> 5;
                int wc = (tid & 31) * 4;
                #pragma unroll
                for (int h2 = 0; h2 < 4; h2++){
                    int r = wr + 8 * h2;
                    *(float4*)&Ws[r * NH + wc] = *(const float4*)(W + (size_t)(k0 + r) * NH + wc);
                }
            }
            __syncthreads();
            #pragma unroll
            for (int kk = 0; kk < 32; kk++){
                float4 wv = *(const float4*)&Ws[kk * NH + cq * 4];
                #pragma unroll
                for (int i = 0; i < 8; i++){
                    float xv = Xs[(rq + 8*i) * 132 + k0 + kk];
                    acc[i][0] += xv * wv.x; acc[i][1] += xv * wv.y;
                    acc[i][2] += xv * wv.z; acc[i][3] += xv * wv.w;
                }
            }
        }
        float b0 = bb[cq*4+0], b1 = bb[cq*4+1], b2 = bb[cq*4+2], b3 = bb[cq*4+3];
        #pragma unroll
        for (int i = 0; i < 8; i++){
            int nid = nids[rq + 8*i];
            if (nid < 0) continue;
            float v0 = acc[i][0]+b0, v1 = acc[i][1]+b1, v2 = acc[i][2]+b2, v3 = acc[i][3]+b3;
            if (m == 1){
                ushort4 s4; s4.x=f2bf(v0); s4.y=f2bf(v1); s4.z=f2bf(v2); s4.w=f2bf(v3);
                *(ushort4*)(Knb + (size_t)nid * NH + cq * 4) = s4;
            } else {
                float* OUT = (m == 0) ? Qn : Vn;
                *(float4*)(OUT + (size_t)nid * NH + cq * 4) = make_float4(v0, v1, v2, v3);
            }
        }
    }
}

// ------------- RTE tables ----------------
__global__ void GNN_rte_tab(const float* __restrict__ rte_emb, const float* __restrict__ rW,
                            const float* __restrict__ rb, float* __restrict__ tab){
    int m = blockIdx.x, j = threadIdx.x;
    __shared__ float e[NH];
    e[j] = rte_emb[m * NH + j];
    __syncthreads();
    float a = rb[j];
    #pragma unroll 8
    for (int d = 0; d < NH; d++) a += e[d] * rW[d * NH + j];
    tab[m * NH + j] = a;
}

// RK output bf16 (attention gather path); RV stays fp32 (feeds RVM xform).
__global__ void GNN_rte_proj(const float* __restrict__ tab, const float* __restrict__ WkL,
                             const float* __restrict__ WvL, unsigned short* __restrict__ RKb,
                             float* __restrict__ RV){
    int m = blockIdx.x, j = threadIdx.x;
    int sel = blockIdx.y; int t = sel >> 1; int which = sel & 1;
    const float* W = (which ? WvL : WkL) + (size_t)t * NH * NH;
    __shared__ float e[NH];
    e[j] = tab[m * NH + j];
    __syncthreads();
    float a = 0.f;
    #pragma unroll 8
    for (int d = 0; d < NH; d++) a += e[d] * W[d * NH + j];
    if (which) RV[(size_t)(t * 240 + m) * NH + j] = a;
    else       RKb[(size_t)(t * 240 + m) * NH + j] = f2bf(a);
}

// ------------- row transform (bf16 out), per head h:
// TRANSPOSE=1 (QA):  out[d] = p * sum_c A[h][d][c] * x[h*32+c]   (contract 2nd idx)
// TRANSPOSE=0 (VM):  out[c] =     sum_d M[h][d][c] * x[h*32+d]   (contract 1st idx,
//                                 matches reference einsum 'ehd,hdk->ehk')
template<int SCALE, int TRANSPOSE>
__global__ __launch_bounds__(256) void GNN_xform(
    const float* __restrict__ X, int rows,
    const float* __restrict__ A5, const float* __restrict__ relP,
    unsigned short* __restrict__ outb)
{
    __shared__ float At[NHEAD * DK * DK];   // At[h*1024 + sum_idx*32 + out_idx]
    int tid = threadIdx.x;
    int hw = tid >> 5, lane = tid & 31, h = lane >> 3, dl = (lane & 7) * 4;
    float4 x4[8];
    #pragma unroll
    for (int it = 0; it < 8; it++){
        int row = blockIdx.x * 64 + it * 8 + hw;
        x4[it] = make_float4(0.f, 0.f, 0.f, 0.f);
        if (row < rows) x4[it] = *(const float4*)(X + (size_t)row * NH + lane * 4);
    }
    for (int r = 0; r < NREL; r++){
        __syncthreads();
        const float* Ar = A5 + (size_t)r * NHEAD * DK * DK;
        if (TRANSPOSE){
            for (int x = tid; x < NHEAD * DK * DK; x += 256){
                int hh = x >> 10, rem = x & 1023, dd = rem >> 5, cc = rem & 31;
                At[hh * 1024 + cc * 32 + dd] = Ar[x];   // [c][d] = A[d][c]
            }
        } else {
            for (int x = tid; x < NHEAD * DK * DK; x += 256) At[x] = Ar[x];  // [d][c]
        }
        __syncthreads();
        float p = 1.f;
        if (SCALE) p = relP[r * NHEAD + h] * RSQRT_DK;
        for (int it = 0; it < 8; it++){
            int row = blockIdx.x * 64 + it * 8 + hw;
            float4 q4 = x4[it];
            float ox = 0.f, oy = 0.f, oz = 0.f, ow = 0.f;
            #pragma unroll
            for (int c = 0; c < 32; c++){               // c = contraction index
                float comp = ((c & 3) == 0) ? q4.x : ((c & 3) == 1) ? q4.y
                           : ((c & 3) == 2) ? q4.z : q4.w;
                float qc = __shfl(comp, h * 8 + (c >> 2), 32);
                float4 av = *(const float4*)&At[h * 1024 + c * 32 + dl];
                ox += qc * av.x; oy += qc * av.y; oz += qc * av.z; ow += qc * av.w;
            }
            if (row < rows){
                size_t o = ((size_t)row * NREL + r) * NH + lane * 4;
                ushort4 s4;
                s4.x = f2bf(ox*p); s4.y = f2bf(oy*p); s4.z = f2bf(oz*p); s4.w = f2bf(ow*p);
                *(ushort4*)(outb + o) = s4;
            }
        }
    }
}

// ------------- fused attention: single-pass online softmax, all-bf16 gathers -------------
__global__ __launch_bounds__(256) void GNN_attn(
    const unsigned short* __restrict__ Knb, const unsigned short* __restrict__ RKb,
    const unsigned short* __restrict__ QAb, const unsigned short* __restrict__ VMb,
    const unsigned short* __restrict__ RVMb,
    const int* __restrict__ rowptr, const int* __restrict__ csr_e,
    const int* __restrict__ esrc, const int* __restrict__ etype,
    const int* __restrict__ etime, const int* __restrict__ ntype,
    float* __restrict__ aggr)
{
    int tid = threadIdx.x;
    int hw = tid >> 5, lane = tid & 31;
    int i = blockIdx.x * 8 + hw;
    if (i >= NN) return;                    // no barriers in this kernel
    size_t qoff = (size_t)i * NREL * NH + lane * 4;
    ushort4 u0 = *(const ushort4*)(QAb + qoff);
    ushort4 u1 = *(const ushort4*)(QAb + qoff + NH);
    ushort4 u2 = *(const ushort4*)(QAb + qoff + 2 * NH);
    ushort4 u3 = *(const ushort4*)(QAb + qoff + 3 * NH);
    ushort4 u4 = *(const ushort4*)(QAb + qoff + 4 * NH);
    float4 qa0 = make_float4(bf2f(u0.x), bf2f(u0.y), bf2f(u0.z), bf2f(u0.w));
    float4 qa1 = make_float4(bf2f(u1.x), bf2f(u1.y), bf2f(u1.z), bf2f(u1.w));
    float4 qa2v = make_float4(bf2f(u2.x), bf2f(u2.y), bf2f(u2.z), bf2f(u2.w));
    float4 qa3 = make_float4(bf2f(u3.x), bf2f(u3.y), bf2f(u3.z), bf2f(u3.w));
    float4 qa4 = make_float4(bf2f(u4.x), bf2f(u4.y), bf2f(u4.z), bf2f(u4.w));
    int beg = rowptr[i], end = rowptr[i + 1];
    float mx = -3.4e38f, den = 0.f;
    float ax = 0.f, ay = 0.f, az = 0.f, aw = 0.f;
    int e = 0, s = 0, r = 0, tm = 0, st = 0;
    if (beg < end){ e = csr_e[beg]; s = esrc[e]; r = etype[e]; tm = etime[e]; st = ntype[s]; }
    for (int k = beg; k < end; k++){
        int e2 = 0, s2 = 0, r2 = 0, tm2 = 0, st2 = 0;
        if (k + 1 < end){                   // 1-deep index prefetch
            e2 = csr_e[k+1]; s2 = esrc[e2]; r2 = etype[e2]; tm2 = etime[e2]; st2 = ntype[s2];
        }
        ushort4 ku = *(const ushort4*)(Knb + (size_t)s * NH + lane * 4);
        ushort4 rku = *(const ushort4*)(RKb + (size_t)(st * 240 + tm) * NH + lane * 4);
        float4 q = (r == 0) ? qa0 : (r == 1) ? qa1 : (r == 2) ? qa2v : (r == 3) ? qa3 : qa4;
        float pv = (bf2f(ku.x) + bf2f(rku.x)) * q.x + (bf2f(ku.y) + bf2f(rku.y)) * q.y
                 + (bf2f(ku.z) + bf2f(rku.z)) * q.z + (bf2f(ku.w) + bf2f(rku.w)) * q.w;
        pv += __shfl_xor(pv, 1, 32);
        pv += __shfl_xor(pv, 2, 32);
        pv += __shfl_xor(pv, 4, 32);        // all 8 lanes of the head now hold the score
        float a = pv;                       // relP/sqrt(dk) already folded into QA
        if (a > mx){
            float sc = expf(mx - a);        // first edge: expf(-3.4e38-a) == 0
            den *= sc; ax *= sc; ay *= sc; az *= sc; aw *= sc;
            mx = a;
        }
        float ex = expf(a - mx);
        den += ex;
        ushort4 vm4 = *(const ushort4*)(VMb + ((size_t)s * NREL + r) * NH + lane * 4);
        ushort4 rv4 = *(const ushort4*)(RVMb + ((size_t)(st * 240 + tm) * NREL + r) * NH + lane * 4);
        float vx = bf2f(vm4.x) + bf2f(rv4.x);
        float vy = bf2f(vm4.y) + bf2f(rv4.y);
        float vz = bf2f(vm4.z) + bf2f(rv4.z);
        float vw = bf2f(vm4.w) + bf2f(rv4.w);
        ax += ex * vx; ay += ex * vy; az += ex * vz; aw += ex * vw;
        e = e2; s = s2; r = r2; tm = tm2; st = st2;
    }
    float inv = 1.f / (den + 1e-16f);
    *(float4*)(aggr + (size_t)i * NH + lane * 4) =
        make_float4(gelu_f(ax * inv), gelu_f(ay * inv), gelu_f(az * inv), gelu_f(aw * inv));
}

extern "C" void kernel_launch(void* const* d_in, const int* in_sizes, int n_in,
                              void* d_out, int out_size, void* d_ws, size_t ws_size,
                              hipStream_t stream)
{
    const float* node_feature = (const float*)d_in[0];
    const float* adapt_W = (const float*)d_in[1];
    const float* adapt_b = (const float*)d_in[2];
    const float* Wk = (const float*)d_in[3];
    const float* bk = (const float*)d_in[4];
    const float* Wq = (const float*)d_in[5];
    const float* bq = (const float*)d_in[6];
    const float* Wv = (const float*)d_in[7];
    const float* bv = (const float*)d_in[8];
    const float* Wa = (const float*)d_in[9];
    const float* ba = (const float*)d_in[10];
    const float* rel_pri = (const float*)d_in[11];
    const float* rel_att = (const float*)d_in[12];
    const float* rel_msg = (const float*)d_in[13];
    const float* skip = (const float*)d_in[14];
    const float* rte_emb = (const float*)d_in[15];
    const float* rte_W = (const float*)d_in[16];
    const float* rte_b = (const float*)d_in[17];
    const int* node_type = (const int*)d_in[18];
    const int* edge_index = (const int*)d_in[19];
    const int* edge_type = (const int*)d_in[20];
    const int* edge_time = (const int*)d_in[21];
    const int* esrc = edge_index;          // row 0 = source j
    const int* edst = edge_index + NE;     // row 1 = target i

    // workspace budget: ~225 MB total (under the round-3-proven ~236 MB bound)
    char* p = (char*)d_ws;
    auto alloc = [&](size_t bytes) -> char* {
        char* r = p; p += (bytes + 255) & ~(size_t)255; return r;
    };
    float* hA    = (float*)alloc((size_t)NN * NH * 4);
    float* Qn    = (float*)alloc((size_t)NN * NH * 4);   // aggr aliases this after xform(QA)
    unsigned short* Knb = (unsigned short*)alloc((size_t)NN * NH * 2);   // bf16 K
    float* Vn    = (float*)alloc((size_t)NN * NH * 4);
    unsigned short* QAb  = (unsigned short*)alloc((size_t)NN * NREL * NH * 2);   // 64 MB bf16
    unsigned short* VMb  = (unsigned short*)alloc((size_t)NN * NREL * NH * 2);   // 64 MB bf16
    unsigned short* RVMb = (unsigned short*)alloc((size_t)NTYPE * 240 * NREL * NH * 2);
    float* rtab  = (float*)alloc((size_t)240 * NH * 4);
    unsigned short* RKb = (unsigned short*)alloc((size_t)NTYPE * 240 * NH * 2);  // bf16 RK
    float* RV    = (float*)alloc((size_t)NTYPE * 240 * NH * 4);
    int* nperm   = (int*)alloc((size_t)NTYPE * NN * 4);
    int* rowptr  = (int*)alloc((size_t)(NN + 1) * 4);
    int* csr_e   = (int*)alloc((size_t)NE * 4);
    int* deg     = (int*)alloc((size_t)2 * NN * 4);      // deg+cursor one block: one memset
    int* cursor  = deg + NN;
    int* bsum    = (int*)alloc(256 * 4);
    int* bbase   = (int*)alloc(256 * 4);
    int* ncur    = (int*)alloc(64);
    float* aggr  = Qn;    // Qn dead after GNN_xform(QA)

    hipMemsetAsync(ncur, 0, 64, stream);
    hipMemsetAsync(deg, 0, (size_t)2 * NN * 4, stream);

    GNN_nscatter<<<(NN + 255) / 256, 256, 0, stream>>>(node_type, ncur, nperm);
    GNN_deg<<<(NE + 255) / 256, 256, 0, stream>>>(edst, deg);
    GNN_scan1<<<NSCAN_BLK, 256, 0, stream>>>(deg, rowptr, bsum);
    GNN_scan2<<<1, 256, 0, stream>>>(bsum, bbase);
    GNN_scan3<<<NSCAN_BLK, 256, 0, stream>>>(rowptr, bbase);
    GNN_csr_scatter<<<(NE + 255) / 256, 256, 0, stream>>>(edst, rowptr, cursor, csr_e);

    dim3 ggrid((NN + BN - 1) / BN, NTYPE);
    GNN_ptype_gemm<0><<<ggrid, 256, 0, stream>>>(node_feature, INDIM, adapt_W, adapt_b,
                                                 nullptr, nullptr, nperm, ncur, hA);
    const float* hin = hA;
    for (int l = 0; l < 2; l++){
        const float* WkL = Wk + (size_t)l * NTYPE * NH * NH;
        const float* WqL = Wq + (size_t)l * NTYPE * NH * NH;
        const float* WvL = Wv + (size_t)l * NTYPE * NH * NH;
        const float* WaL = Wa + (size_t)l * NTYPE * NH * NH;
        const float* bkL = bk + (size_t)l * NTYPE * NH;
        const float* bqL = bq + (size_t)l * NTYPE * NH;
        const float* bvL = bv + (size_t)l * NTYPE * NH;
        const float* baL = ba + (size_t)l * NTYPE * NH;
        const float* relA = rel_att + (size_t)l * NREL * NHEAD * DK * DK;
        const float* relM = rel_msg + (size_t)l * NREL * NHEAD * DK * DK;
        const float* relP = rel_pri + (size_t)l * NREL * NHEAD;

        GNN_rte_tab<<<240, 128, 0, stream>>>(rte_emb, rte_W + (size_t)l * NH * NH,
                                             rte_b + (size_t)l * NH, rtab);
        GNN_rte_proj<<<dim3(240, NTYPE * 2), 128, 0, stream>>>(rtab, WkL, WvL, RKb, RV);

        GNN_qkv<<<ggrid, 256, 0, stream>>>(hin, WqL, WkL, WvL, bqL, bkL, bvL,
                                           nperm, ncur, Qn, Knb, Vn);

        // QA: contract A's 2nd index (k . A q)  -> TRANSPOSE=1
        GNN_xform<1,1><<<(NN + 63) / 64, 256, 0, stream>>>(Qn, NN, relA, relP, QAb);
        // VM/RVM: contract M's 1st index (v^T M) -> TRANSPOSE=0
        GNN_xform<0,0><<<(NN + 63) / 64, 256, 0, stream>>>(Vn, NN, relM, nullptr, VMb);
        GNN_xform<0,0><<<(NTYPE * 240 + 63) / 64, 256, 0, stream>>>(RV, NTYPE * 240, relM,
                                                                    nullptr, RVMb);

        GNN_attn<<<(NN + 7) / 8, 256, 0, stream>>>(
            Knb, RKb, QAb, VMb, RVMb, rowptr, csr_e, esrc, edge_type, edge_time, node_type,
            aggr);

        float* hout = (l == 0) ? hA : (float*)d_out;   // l==0 in-place on hA is safe:
        GNN_ptype_gemm<2><<<ggrid, 256, 0, stream>>>(  // epilogue reads Hprev elem then
            aggr, NH, WaL, baL, skip + (size_t)l * NTYPE, hin,   // writes same elem, same thread
            nperm, ncur, hout);
        hin = hout;
    }
}